// Round 1
// baseline (2425.700 us; speedup 1.0000x reference)
//
#include <hip/hip_runtime.h>
#include <math.h>

// Sizes (fixed for this problem)
#define NB   16
#define NCIN 512
#define NL   1024
#define NCOUT 1024
#define NK   5
#define NDW  512
#define NHW  196

// ---------------------------------------------------------------------------
// K1: weight norm.  w[o,i,k] = g[o]/||v[o,:,:]|| * v[o,i,k]
// ---------------------------------------------------------------------------
__global__ __launch_bounds__(256) void wnorm_kernel(
    const float* __restrict__ v, const float* __restrict__ g,
    float* __restrict__ w) {
  const int o = blockIdx.x;
  const float* vr = v + (size_t)o * (NCIN * NK);
  float s = 0.f;
  for (int j = threadIdx.x; j < NCIN * NK; j += 256) {
    float t = vr[j];
    s += t * t;
  }
  for (int off = 32; off; off >>= 1) s += __shfl_down(s, off, 64);
  __shared__ float red[4];
  __shared__ float scale_s;
  const int wid = threadIdx.x >> 6;
  if ((threadIdx.x & 63) == 0) red[wid] = s;
  __syncthreads();
  if (threadIdx.x == 0) {
    float tot = red[0] + red[1] + red[2] + red[3];
    scale_s = g[o] / sqrtf(tot);
  }
  __syncthreads();
  const float scale = scale_s;
  float* wr = w + (size_t)o * (NCIN * NK);
  for (int j = threadIdx.x; j < NCIN * NK; j += 256) wr[j] = vr[j] * scale;
}

// ---------------------------------------------------------------------------
// K2: conv1d (left zero-pad 4, causal window) + bias + GLU.
// h[b,c,l] = (convA + ba) * sigmoid(convB + bb),  c in [0,512), l in [0,1024)
// convA uses w rows [0,512), convB uses w rows [512,1024).
// Tile: 64 c x 64 l per block, one b.  K-chunks of 8 input channels.
// ---------------------------------------------------------------------------
__global__ __launch_bounds__(256) void conv_glu_kernel(
    const float* __restrict__ x, const float* __restrict__ w,
    const float* __restrict__ conv_b, float* __restrict__ h) {
  const int b  = blockIdx.z;
  const int c0 = blockIdx.y * 64;
  const int l0 = blockIdx.x * 64;
  const int tid = threadIdx.x;
  const int tx = tid & 15;   // -> l group (4 consecutive l)
  const int ty = tid >> 4;   // -> c group (4 consecutive c)

  __shared__ float xs[8][68];     // [i][j]: x[b, i0+i, l0 + j - 4]
  __shared__ float wa[40][68];    // [i*5+dk][c]
  __shared__ float wb[40][68];

  float accA[4][4], accB[4][4];
#pragma unroll
  for (int i = 0; i < 4; ++i)
#pragma unroll
    for (int j = 0; j < 4; ++j) { accA[i][j] = 0.f; accB[i][j] = 0.f; }

  const float* xb = x + (size_t)b * NCIN * NL;

  for (int i0 = 0; i0 < NCIN; i0 += 8) {
    __syncthreads();
    for (int idx = tid; idx < 8 * 68; idx += 256) {
      int i = idx / 68, j = idx % 68;
      int gl = l0 + j - 4;
      xs[i][j] = (gl >= 0) ? xb[(size_t)(i0 + i) * NL + gl] : 0.f;
    }
    for (int idx = tid; idx < 64 * 40; idx += 256) {
      int c = idx / 40, t = idx % 40;
      wa[t][c] = w[(size_t)(c0 + c) * (NCIN * NK) + i0 * NK + t];
      wb[t][c] = w[(size_t)(c0 + c + 512) * (NCIN * NK) + i0 * NK + t];
    }
    __syncthreads();
#pragma unroll
    for (int i = 0; i < 8; ++i) {
      float xv[9];
      float4 xlo = *(const float4*)&xs[i][tx * 4];
      float4 xhi = *(const float4*)&xs[i][tx * 4 + 4];
      xv[0] = xlo.x; xv[1] = xlo.y; xv[2] = xlo.z; xv[3] = xlo.w;
      xv[4] = xhi.x; xv[5] = xhi.y; xv[6] = xhi.z; xv[7] = xhi.w;
      xv[8] = xs[i][tx * 4 + 8];
#pragma unroll
      for (int dk = 0; dk < NK; ++dk) {
        float4 av = *(const float4*)&wa[i * 5 + dk][ty * 4];
        float4 bv = *(const float4*)&wb[i * 5 + dk][ty * 4];
        float aarr[4] = {av.x, av.y, av.z, av.w};
        float barr[4] = {bv.x, bv.y, bv.z, bv.w};
#pragma unroll
        for (int cc = 0; cc < 4; ++cc)
#pragma unroll
          for (int r = 0; r < 4; ++r) {
            accA[cc][r] += aarr[cc] * xv[r + dk];
            accB[cc][r] += barr[cc] * xv[r + dk];
          }
      }
    }
  }

#pragma unroll
  for (int cc = 0; cc < 4; ++cc) {
    int c = c0 + ty * 4 + cc;
    float ba = conv_b[c], bb = conv_b[c + 512];
    float4 o4;
    float ov[4];
#pragma unroll
    for (int r = 0; r < 4; ++r) {
      float aa = accA[cc][r] + ba;
      float bg = accB[cc][r] + bb;
      ov[r] = aa * (1.f / (1.f + __expf(-bg)));
    }
    o4.x = ov[0]; o4.y = ov[1]; o4.z = ov[2]; o4.w = ov[3];
    *(float4*)&h[((size_t)b * NDW + c) * NL + l0 + tx * 4] = o4;
  }
}

// ---------------------------------------------------------------------------
// K3: q[b,l,a] = sum_c h[b,c,l] * fc1_w[a,c] + fc1_b[a] + we[b,l,a]
// Tile 64 l x 64 a per block, one b.  K-chunks of 16 c.
// ---------------------------------------------------------------------------
__global__ __launch_bounds__(256) void fc1_kernel(
    const float* __restrict__ h, const float* __restrict__ fw_g,
    const float* __restrict__ fb, const float* __restrict__ we,
    float* __restrict__ q) {
  const int b  = blockIdx.z;
  const int a0 = blockIdx.y * 64;
  const int l0 = blockIdx.x * 64;
  const int tid = threadIdx.x;
  const int tx = tid & 15;   // -> a group
  const int ty = tid >> 4;   // -> l group

  __shared__ float hs[16][68];  // [c][l]
  __shared__ float fw[16][68];  // [c][a]

  float acc[4][4];  // [r(l)][j(a)]
#pragma unroll
  for (int r = 0; r < 4; ++r)
#pragma unroll
    for (int j = 0; j < 4; ++j) acc[r][j] = 0.f;

  const float* hb = h + (size_t)b * NDW * NL;

  for (int c0 = 0; c0 < NDW; c0 += 16) {
    __syncthreads();
    for (int idx = tid; idx < 1024; idx += 256) {
      int i = idx >> 6, lj = idx & 63;
      hs[i][lj] = hb[(size_t)(c0 + i) * NL + l0 + lj];
    }
    for (int idx = tid; idx < 1024; idx += 256) {
      int aj = idx >> 4, i = idx & 15;
      fw[i][aj] = fw_g[(size_t)(a0 + aj) * NDW + c0 + i];
    }
    __syncthreads();
#pragma unroll
    for (int i = 0; i < 16; ++i) {
      float4 wv = *(const float4*)&fw[i][tx * 4];
      float4 hv = *(const float4*)&hs[i][ty * 4];
      float wr[4] = {wv.x, wv.y, wv.z, wv.w};
      float hr[4] = {hv.x, hv.y, hv.z, hv.w};
#pragma unroll
      for (int r = 0; r < 4; ++r)
#pragma unroll
        for (int j = 0; j < 4; ++j) acc[r][j] += hr[r] * wr[j];
    }
  }

  float4 fb4 = *(const float4*)&fb[a0 + tx * 4];
#pragma unroll
  for (int r = 0; r < 4; ++r) {
    int l = l0 + ty * 4 + r;
    size_t base = ((size_t)b * NL + l) * NDW + a0 + tx * 4;
    float4 wev = *(const float4*)&we[base];
    float4 o4;
    o4.x = acc[r][0] + fb4.x + wev.x;
    o4.y = acc[r][1] + fb4.y + wev.y;
    o4.z = acc[r][2] + fb4.z + wev.z;
    o4.w = acc[r][3] + fb4.w + wev.w;
    *(float4*)&q[base] = o4;
  }
}

// ---------------------------------------------------------------------------
// K4: attention.  Per block: one b, 16 query rows (l0..l0+15).
//  score[l,p] = sum_a q[l,a] feat[a,p];  attn = softmax_p;  (attn -> output)
//  ctx[l,a]   = sum_p attn[l,p] feat[a,p]   (ctx aliases q workspace)
// ---------------------------------------------------------------------------
__global__ __launch_bounds__(256) void attn_kernel(
    const float* __restrict__ q, const float* __restrict__ feat,
    float* __restrict__ ctx, float* __restrict__ attn_out) {
  const int b  = blockIdx.y;
  const int l0 = blockIdx.x * 16;
  const int tid = threadIdx.x;

  __shared__ float qs[16][516];
  __shared__ float fs[32][208];
  __shared__ float as[16][212];

  for (int idx = tid; idx < 16 * 512; idx += 256) {
    int l = idx >> 9, a = idx & 511;
    qs[l][a] = q[((size_t)b * NL + l0 + l) * NDW + a];
  }
  // zero the fs column pad [196,208) once; never overwritten after
  for (int idx = tid; idx < 32 * 12; idx += 256) {
    int i = idx / 12, p = 196 + idx % 12;
    fs[i][p] = 0.f;
  }
  __syncthreads();

  const float* fbp = feat + (size_t)b * NDW * NHW;

  // ---- phase A: scores ----
  const int lA  = tid >> 4;  // query row
  const int txA = tid & 15;  // p = txA + 16*pp
  float sc[13];
#pragma unroll
  for (int pp = 0; pp < 13; ++pp) sc[pp] = 0.f;

  for (int a0 = 0; a0 < NDW; a0 += 32) {
    for (int idx = tid; idx < 32 * 196; idx += 256) {
      int i = idx / 196, p = idx % 196;
      fs[i][p] = fbp[(size_t)(a0 + i) * NHW + p];
    }
    __syncthreads();
#pragma unroll 4
    for (int i = 0; i < 32; ++i) {
      float qv = qs[lA][a0 + i];
#pragma unroll
      for (int pp = 0; pp < 13; ++pp) {
        sc[pp] += qv * fs[i][txA + (pp << 4)];  // pad cols are 0
      }
    }
    __syncthreads();
  }

  // softmax over valid p (p = txA+16*pp < 196)
  const bool v12 = (txA < 4);
  float mx = -1e30f;
#pragma unroll
  for (int pp = 0; pp < 12; ++pp) mx = fmaxf(mx, sc[pp]);
  if (v12) mx = fmaxf(mx, sc[12]);
  for (int off = 1; off < 16; off <<= 1) mx = fmaxf(mx, __shfl_xor(mx, off, 64));
  float ex[13];
  float sum = 0.f;
#pragma unroll
  for (int pp = 0; pp < 12; ++pp) { ex[pp] = __expf(sc[pp] - mx); sum += ex[pp]; }
  ex[12] = v12 ? __expf(sc[12] - mx) : 0.f;
  sum += ex[12];
  for (int off = 1; off < 16; off <<= 1) sum += __shfl_xor(sum, off, 64);
  const float inv = 1.f / sum;

  float* ao = attn_out + ((size_t)b * NL + l0 + lA) * NHW;
#pragma unroll
  for (int pp = 0; pp < 13; ++pp) {
    int p = txA + (pp << 4);
    float vv = ex[pp] * inv;
    if (p < NHW) {
      as[lA][p] = vv;
      ao[p] = vv;
    }
  }

  // ---- phase B: ctx ----
  const int lB  = tid & 15;
  const int tyB = tid >> 4;
  for (int a0 = 0; a0 < NDW; a0 += 32) {
    __syncthreads();  // also covers as[] visibility on first iter
    for (int idx = tid; idx < 32 * 196; idx += 256) {
      int i = idx / 196, p = idx % 196;
      fs[i][p] = fbp[(size_t)(a0 + i) * NHW + p];
    }
    __syncthreads();
#pragma unroll
    for (int k = 0; k < 2; ++k) {
      int ar = tyB + (k << 4);
      float s = 0.f;
#pragma unroll
      for (int p4 = 0; p4 < 49; ++p4) {
        float4 av = *(const float4*)&as[lB][p4 * 4];
        float4 fv = *(const float4*)&fs[ar][p4 * 4];
        s += av.x * fv.x + av.y * fv.y + av.z * fv.z + av.w * fv.w;
      }
      ctx[((size_t)b * NL + l0 + lB) * NDW + a0 + ar] = s;
    }
  }
}

// ---------------------------------------------------------------------------
// K5: out[b,c,l] = sum_a ctx[b,l,a] fc2_w[c,a] + fc2_b[c] + h[b,c,l] + x[b,c,l]
// Tile 64 c x 64 l, one b.  K-chunks of 16 a.
// ---------------------------------------------------------------------------
__global__ __launch_bounds__(256) void fc2_kernel(
    const float* __restrict__ ctx, const float* __restrict__ fw2g,
    const float* __restrict__ fb2, const float* __restrict__ h,
    const float* __restrict__ x, float* __restrict__ out0) {
  const int b  = blockIdx.z;
  const int c0 = blockIdx.y * 64;
  const int l0 = blockIdx.x * 64;
  const int tid = threadIdx.x;
  const int tx = tid & 15;   // -> l group
  const int ty = tid >> 4;   // -> c group

  __shared__ float cs[16][68];  // [a][l]
  __shared__ float fw[16][68];  // [a][c]

  float acc[4][4];  // [cc][r(l)]
#pragma unroll
  for (int i = 0; i < 4; ++i)
#pragma unroll
    for (int j = 0; j < 4; ++j) acc[i][j] = 0.f;

  for (int a0 = 0; a0 < NDW; a0 += 16) {
    __syncthreads();
    for (int idx = tid; idx < 1024; idx += 256) {
      int l = idx >> 4, i = idx & 15;
      cs[i][l] = ctx[((size_t)b * NL + l0 + l) * NDW + a0 + i];
    }
    for (int idx = tid; idx < 1024; idx += 256) {
      int c = idx >> 4, i = idx & 15;
      fw[i][c] = fw2g[(size_t)(c0 + c) * NDW + a0 + i];
    }
    __syncthreads();
#pragma unroll
    for (int i = 0; i < 16; ++i) {
      float4 lv = *(const float4*)&cs[i][tx * 4];
      float4 cv = *(const float4*)&fw[i][ty * 4];
      float lr[4] = {lv.x, lv.y, lv.z, lv.w};
      float cr[4] = {cv.x, cv.y, cv.z, cv.w};
#pragma unroll
      for (int cc = 0; cc < 4; ++cc)
#pragma unroll
        for (int r = 0; r < 4; ++r) acc[cc][r] += cr[cc] * lr[r];
    }
  }

#pragma unroll
  for (int cc = 0; cc < 4; ++cc) {
    int c = c0 + ty * 4 + cc;
    size_t base = ((size_t)b * NDW + c) * NL + l0 + tx * 4;
    float4 hv = *(const float4*)&h[base];
    float4 xv = *(const float4*)&x[base];
    float bias = fb2[c];
    float4 o4;
    o4.x = acc[cc][0] + bias + hv.x + xv.x;
    o4.y = acc[cc][1] + bias + hv.y + xv.y;
    o4.z = acc[cc][2] + bias + hv.z + xv.z;
    o4.w = acc[cc][3] + bias + hv.w + xv.w;
    *(float4*)&out0[base] = o4;
  }
}

// ---------------------------------------------------------------------------
extern "C" void kernel_launch(void* const* d_in, const int* in_sizes, int n_in,
                              void* d_out, int out_size, void* d_ws, size_t ws_size,
                              hipStream_t stream) {
  const float* x      = (const float*)d_in[0];
  const float* we     = (const float*)d_in[1];
  const float* img    = (const float*)d_in[2];
  // d_in[3] prev_attn: unused by reference
  const float* conv_v = (const float*)d_in[4];
  const float* conv_g = (const float*)d_in[5];
  const float* conv_b = (const float*)d_in[6];
  const float* fc1_w  = (const float*)d_in[7];
  const float* fc1_b  = (const float*)d_in[8];
  const float* fc2_w  = (const float*)d_in[9];
  const float* fc2_b  = (const float*)d_in[10];

  float* out0     = (float*)d_out;          // (16,512,1024)
  float* out_we   = out0 + 8388608;         // (16,1024,512)
  float* out_img  = out_we + 8388608;       // (16,512,14,14)
  float* out_attn = out_img + 1605632;      // (16,1024,196)

  float* ws  = (float*)d_ws;
  float* w   = ws;                          // 1024*2560      = 2,621,440
  float* h   = w + 2621440;                 // 16*512*1024    = 8,388,608
  float* q   = h + 8388608;                 // 16*1024*512    = 8,388,608
  float* ctx = q;                           // aliases q (safe: per-block q rows
                                            // staged to LDS before ctx writes)

  wnorm_kernel<<<dim3(NCOUT), 256, 0, stream>>>(conv_v, conv_g, w);
  conv_glu_kernel<<<dim3(16, 8, NB), 256, 0, stream>>>(x, w, conv_b, h);
  fc1_kernel<<<dim3(16, 8, NB), 256, 0, stream>>>(h, fc1_w, fc1_b, we, q);
  attn_kernel<<<dim3(64, NB), 256, 0, stream>>>(q, img, ctx, out_attn);
  fc2_kernel<<<dim3(16, 8, NB), 256, 0, stream>>>(ctx, fc2_w, fc2_b, h, x, out0);

  hipMemcpyAsync(out_we, we, (size_t)8388608 * sizeof(float),
                 hipMemcpyDeviceToDevice, stream);
  hipMemcpyAsync(out_img, img, (size_t)1605632 * sizeof(float),
                 hipMemcpyDeviceToDevice, stream);
}

// Round 2
// 1231.073 us; speedup vs baseline: 1.9704x; 1.9704x over previous
//
#include <hip/hip_runtime.h>
#include <math.h>

// Sizes (fixed for this problem)
#define NB   16
#define NCIN 512
#define NL   1024
#define NCOUT 1024
#define NK   5
#define NDW  512
#define NHW  196

typedef unsigned short ushort_t;
typedef unsigned int uint_t;
typedef __attribute__((ext_vector_type(8))) short bf16x8;
typedef __attribute__((ext_vector_type(4))) float f32x4;

static __device__ __forceinline__ ushort_t f2bf(float f) {
  uint_t u = __builtin_bit_cast(uint_t, f);
  u += 0x7fff + ((u >> 16) & 1);  // round-to-nearest-even
  return (ushort_t)(u >> 16);
}

// ---------------------------------------------------------------------------
// K1: weight norm -> permuted bf16 weights.
// wperm[dk][co][ci] = bf16( g[co]/||v[co]|| * v[co][ci][dk] )
// ---------------------------------------------------------------------------
__global__ __launch_bounds__(256) void wnorm_kernel(
    const float* __restrict__ v, const float* __restrict__ g,
    ushort_t* __restrict__ wperm) {
  const int o = blockIdx.x;
  const float* vr = v + (size_t)o * (NCIN * NK);
  float s = 0.f;
  for (int j = threadIdx.x; j < NCIN * NK; j += 256) {
    float t = vr[j];
    s += t * t;
  }
  for (int off = 32; off; off >>= 1) s += __shfl_down(s, off, 64);
  __shared__ float red[4];
  __shared__ float scale_s;
  const int wid = threadIdx.x >> 6;
  if ((threadIdx.x & 63) == 0) red[wid] = s;
  __syncthreads();
  if (threadIdx.x == 0) {
    float tot = red[0] + red[1] + red[2] + red[3];
    scale_s = g[o] / sqrtf(tot);
  }
  __syncthreads();
  const float scale = scale_s;
#pragma unroll
  for (int dk = 0; dk < NK; ++dk) {
    for (int ci = threadIdx.x; ci < NCIN; ci += 256) {
      wperm[((size_t)dk * NCOUT + o) * NCIN + ci] = f2bf(vr[ci * NK + dk] * scale);
    }
  }
}

// ---------------------------------------------------------------------------
// K2a: transpose + bf16 convert:  xT[b][l][ci] = bf16(x[b][ci][l])
// 64x64 tiles, LDS pad 65 (scalar LDS ops -> 2-way max conflicts).
// ---------------------------------------------------------------------------
__global__ __launch_bounds__(256) void xpose_kernel(
    const float* __restrict__ x, ushort_t* __restrict__ xT) {
  const int b = blockIdx.z;
  const int ci0 = blockIdx.y * 64;
  const int l0 = blockIdx.x * 64;
  const int tid = threadIdx.x;
  __shared__ float t[64][65];
  const float* xb = x + ((size_t)b * NCIN + ci0) * NL + l0;
#pragma unroll
  for (int r = 0; r < 4; ++r) {
    int row = r * 16 + (tid >> 4);   // ci offset
    int col = (tid & 15) * 4;        // l offset
    float4 v = *(const float4*)&xb[(size_t)row * NL + col];
    t[row][col + 0] = v.x; t[row][col + 1] = v.y;
    t[row][col + 2] = v.z; t[row][col + 3] = v.w;
  }
  __syncthreads();
  ushort_t* xo = xT + ((size_t)b * NL + l0) * NCIN + ci0;
#pragma unroll
  for (int r = 0; r < 4; ++r) {
    int lrow = r * 16 + (tid >> 4);  // l offset
    int cic = (tid & 15) * 4;        // ci offset
    ushort4 o4;
    o4.x = f2bf(t[cic + 0][lrow]);
    o4.y = f2bf(t[cic + 1][lrow]);
    o4.z = f2bf(t[cic + 2][lrow]);
    o4.w = f2bf(t[cic + 3][lrow]);
    *(ushort4*)&xo[(size_t)lrow * NCIN + cic] = o4;
  }
}

// ---------------------------------------------------------------------------
// K2b: conv1d + bias + GLU via bf16 MFMA implicit GEMM.
//   y[co, l] = sum_{dk, ci} wperm[dk][co][ci] * xT[l + dk - 4][ci]
//   h[co, l] = (yA + bA) * sigmoid(yB + bB),  co in [0,512)
// Block: 128 l x (128 A-co + 128 B-co), 4 waves, each wave 64l x 64co both halves.
// K-chunks of 64 ci; 5 taps as outer loop (tap = LDS row shift of the x tile).
// ---------------------------------------------------------------------------
__global__ __launch_bounds__(256, 2) void conv_glu_mfma(
    const ushort_t* __restrict__ xT, const ushort_t* __restrict__ wperm,
    const float* __restrict__ conv_b, float* __restrict__ h) {
  const int b  = blockIdx.z;
  const int c0 = blockIdx.y * 128;   // A-half co tile base (B-half = +512)
  const int l0 = blockIdx.x * 128;
  const int tid = threadIdx.x;
  const int wid = tid >> 6;
  const int lane = tid & 63;
  const int wl = wid & 1;            // wave l sub-tile
  const int wc = wid >> 1;           // wave co sub-tile
  const int quad = lane >> 4;
  const int l16 = lane & 15;

  __shared__ ushort_t lx[128][72];   // rows: l (shifted); cols: 64 ci + 8 pad
  __shared__ ushort_t lw[256][72];   // rows: 128 A-co then 128 B-co

  f32x4 accA[4][4], accB[4][4];
#pragma unroll
  for (int mt = 0; mt < 4; ++mt)
#pragma unroll
    for (int nt = 0; nt < 4; ++nt) {
      accA[mt][nt] = (f32x4){0.f, 0.f, 0.f, 0.f};
      accB[mt][nt] = (f32x4){0.f, 0.f, 0.f, 0.f};
    }

  const ushort_t* xTb = xT + (size_t)b * NL * NCIN;

  for (int dk = 0; dk < NK; ++dk) {
    const int lbase = l0 + dk - 4;
    const ushort_t* wpb = wperm + (size_t)dk * NCOUT * NCIN;
    for (int ci0 = 0; ci0 < NCIN; ci0 += 64) {
      __syncthreads();
      // stage x tile: 128 rows x 64 ci (8 x 16B segs per row)
#pragma unroll
      for (int it = 0; it < 4; ++it) {
        int t = tid + it * 256;
        int r = t >> 3, seg = t & 7;
        int gl = lbase + r;
        uint4 v = make_uint4(0u, 0u, 0u, 0u);
        if (gl >= 0)
          v = *(const uint4*)(xTb + (size_t)gl * NCIN + ci0 + seg * 8);
        *(uint4*)&lx[r][seg * 8] = v;
      }
      // stage w tile: rows 0..127 -> co=c0+r (A), rows 128..255 -> co=512+c0+(r-128) (B)
#pragma unroll
      for (int it = 0; it < 8; ++it) {
        int t = tid + it * 256;
        int r = t >> 3, seg = t & 7;
        int co = (it < 4) ? (c0 + r) : (384 + c0 + r);
        uint4 v = *(const uint4*)(wpb + (size_t)co * NCIN + ci0 + seg * 8);
        *(uint4*)&lw[r][seg * 8] = v;
      }
      __syncthreads();
#pragma unroll
      for (int ks = 0; ks < 2; ++ks) {
        bf16x8 af[4];
#pragma unroll
        for (int mt = 0; mt < 4; ++mt)
          af[mt] = *(const bf16x8*)&lx[wl * 64 + mt * 16 + l16][ks * 32 + quad * 8];
#pragma unroll
        for (int nt = 0; nt < 4; ++nt) {
          bf16x8 bfa = *(const bf16x8*)&lw[wc * 64 + nt * 16 + l16][ks * 32 + quad * 8];
          bf16x8 bfb = *(const bf16x8*)&lw[128 + wc * 64 + nt * 16 + l16][ks * 32 + quad * 8];
#pragma unroll
          for (int mt = 0; mt < 4; ++mt) {
            accA[mt][nt] = __builtin_amdgcn_mfma_f32_16x16x32_bf16(af[mt], bfa, accA[mt][nt], 0, 0, 0);
            accB[mt][nt] = __builtin_amdgcn_mfma_f32_16x16x32_bf16(af[mt], bfb, accB[mt][nt], 0, 0, 0);
          }
        }
      }
    }
  }

  // epilogue: GLU, write h[b][co][l]
#pragma unroll
  for (int nt = 0; nt < 4; ++nt) {
    const int co = c0 + wc * 64 + nt * 16 + l16;   // D col = lane&15
    const float ba = conv_b[co];
    const float bb = conv_b[co + 512];
#pragma unroll
    for (int mt = 0; mt < 4; ++mt) {
      const int l = l0 + wl * 64 + mt * 16 + quad * 4;  // D row = quad*4 + reg
      f32x4 a4 = accA[mt][nt];
      f32x4 b4 = accB[mt][nt];
      float4 o4;
      {
        float aa = a4[0] + ba, bg = b4[0] + bb;
        o4.x = aa * (1.f / (1.f + __expf(-bg)));
        aa = a4[1] + ba; bg = b4[1] + bb;
        o4.y = aa * (1.f / (1.f + __expf(-bg)));
        aa = a4[2] + ba; bg = b4[2] + bb;
        o4.z = aa * (1.f / (1.f + __expf(-bg)));
        aa = a4[3] + ba; bg = b4[3] + bb;
        o4.w = aa * (1.f / (1.f + __expf(-bg)));
      }
      *(float4*)&h[((size_t)b * NDW + co) * NL + l] = o4;
    }
  }
}

// ---------------------------------------------------------------------------
// K3: q[b,l,a] = sum_c h[b,c,l] * fc1_w[a,c] + fc1_b[a] + we[b,l,a]
// ---------------------------------------------------------------------------
__global__ __launch_bounds__(256) void fc1_kernel(
    const float* __restrict__ h, const float* __restrict__ fw_g,
    const float* __restrict__ fb, const float* __restrict__ we,
    float* __restrict__ q) {
  const int b  = blockIdx.z;
  const int a0 = blockIdx.y * 64;
  const int l0 = blockIdx.x * 64;
  const int tid = threadIdx.x;
  const int tx = tid & 15;   // -> a group
  const int ty = tid >> 4;   // -> l group

  __shared__ float hs[16][68];  // [c][l]
  __shared__ float fw[16][68];  // [c][a]

  float acc[4][4];
#pragma unroll
  for (int r = 0; r < 4; ++r)
#pragma unroll
    for (int j = 0; j < 4; ++j) acc[r][j] = 0.f;

  const float* hb = h + (size_t)b * NDW * NL;

  for (int c0 = 0; c0 < NDW; c0 += 16) {
    __syncthreads();
    for (int idx = tid; idx < 1024; idx += 256) {
      int i = idx >> 6, lj = idx & 63;
      hs[i][lj] = hb[(size_t)(c0 + i) * NL + l0 + lj];
    }
    for (int idx = tid; idx < 1024; idx += 256) {
      int aj = idx >> 4, i = idx & 15;
      fw[i][aj] = fw_g[(size_t)(a0 + aj) * NDW + c0 + i];
    }
    __syncthreads();
#pragma unroll
    for (int i = 0; i < 16; ++i) {
      float4 wv = *(const float4*)&fw[i][tx * 4];
      float4 hv = *(const float4*)&hs[i][ty * 4];
      float wr[4] = {wv.x, wv.y, wv.z, wv.w};
      float hr[4] = {hv.x, hv.y, hv.z, hv.w};
#pragma unroll
      for (int r = 0; r < 4; ++r)
#pragma unroll
        for (int j = 0; j < 4; ++j) acc[r][j] += hr[r] * wr[j];
    }
  }

  float4 fb4 = *(const float4*)&fb[a0 + tx * 4];
#pragma unroll
  for (int r = 0; r < 4; ++r) {
    int l = l0 + ty * 4 + r;
    size_t base = ((size_t)b * NL + l) * NDW + a0 + tx * 4;
    float4 wev = *(const float4*)&we[base];
    float4 o4;
    o4.x = acc[r][0] + fb4.x + wev.x;
    o4.y = acc[r][1] + fb4.y + wev.y;
    o4.z = acc[r][2] + fb4.z + wev.z;
    o4.w = acc[r][3] + fb4.w + wev.w;
    *(float4*)&q[base] = o4;
  }
}

// ---------------------------------------------------------------------------
// K4: attention (16 query rows per block)
// ---------------------------------------------------------------------------
__global__ __launch_bounds__(256) void attn_kernel(
    const float* __restrict__ q, const float* __restrict__ feat,
    float* __restrict__ ctx, float* __restrict__ attn_out) {
  const int b  = blockIdx.y;
  const int l0 = blockIdx.x * 16;
  const int tid = threadIdx.x;

  __shared__ float qs[16][516];
  __shared__ float fs[32][208];
  __shared__ float as[16][212];

  for (int idx = tid; idx < 16 * 512; idx += 256) {
    int l = idx >> 9, a = idx & 511;
    qs[l][a] = q[((size_t)b * NL + l0 + l) * NDW + a];
  }
  for (int idx = tid; idx < 32 * 12; idx += 256) {
    int i = idx / 12, p = 196 + idx % 12;
    fs[i][p] = 0.f;
  }
  __syncthreads();

  const float* fbp = feat + (size_t)b * NDW * NHW;

  const int lA  = tid >> 4;
  const int txA = tid & 15;
  float sc[13];
#pragma unroll
  for (int pp = 0; pp < 13; ++pp) sc[pp] = 0.f;

  for (int a0 = 0; a0 < NDW; a0 += 32) {
    for (int idx = tid; idx < 32 * 196; idx += 256) {
      int i = idx / 196, p = idx % 196;
      fs[i][p] = fbp[(size_t)(a0 + i) * NHW + p];
    }
    __syncthreads();
#pragma unroll 4
    for (int i = 0; i < 32; ++i) {
      float qv = qs[lA][a0 + i];
#pragma unroll
      for (int pp = 0; pp < 13; ++pp) {
        sc[pp] += qv * fs[i][txA + (pp << 4)];
      }
    }
    __syncthreads();
  }

  const bool v12 = (txA < 4);
  float mx = -1e30f;
#pragma unroll
  for (int pp = 0; pp < 12; ++pp) mx = fmaxf(mx, sc[pp]);
  if (v12) mx = fmaxf(mx, sc[12]);
  for (int off = 1; off < 16; off <<= 1) mx = fmaxf(mx, __shfl_xor(mx, off, 64));
  float ex[13];
  float sum = 0.f;
#pragma unroll
  for (int pp = 0; pp < 12; ++pp) { ex[pp] = __expf(sc[pp] - mx); sum += ex[pp]; }
  ex[12] = v12 ? __expf(sc[12] - mx) : 0.f;
  sum += ex[12];
  for (int off = 1; off < 16; off <<= 1) sum += __shfl_xor(sum, off, 64);
  const float inv = 1.f / sum;

  float* ao = attn_out + ((size_t)b * NL + l0 + lA) * NHW;
#pragma unroll
  for (int pp = 0; pp < 13; ++pp) {
    int p = txA + (pp << 4);
    float vv = ex[pp] * inv;
    if (p < NHW) {
      as[lA][p] = vv;
      ao[p] = vv;
    }
  }

  const int lB  = tid & 15;
  const int tyB = tid >> 4;
  for (int a0 = 0; a0 < NDW; a0 += 32) {
    __syncthreads();
    for (int idx = tid; idx < 32 * 196; idx += 256) {
      int i = idx / 196, p = idx % 196;
      fs[i][p] = fbp[(size_t)(a0 + i) * NHW + p];
    }
    __syncthreads();
#pragma unroll
    for (int k = 0; k < 2; ++k) {
      int ar = tyB + (k << 4);
      float s = 0.f;
#pragma unroll
      for (int p4 = 0; p4 < 49; ++p4) {
        float4 av = *(const float4*)&as[lB][p4 * 4];
        float4 fv = *(const float4*)&fs[ar][p4 * 4];
        s += av.x * fv.x + av.y * fv.y + av.z * fv.z + av.w * fv.w;
      }
      ctx[((size_t)b * NL + l0 + lB) * NDW + a0 + ar] = s;
    }
  }
}

// ---------------------------------------------------------------------------
// K5: out[b,c,l] = sum_a ctx[b,l,a] fc2_w[c,a] + fc2_b[c] + h[b,c,l] + x[b,c,l]
// ---------------------------------------------------------------------------
__global__ __launch_bounds__(256) void fc2_kernel(
    const float* __restrict__ ctx, const float* __restrict__ fw2g,
    const float* __restrict__ fb2, const float* __restrict__ h,
    const float* __restrict__ x, float* __restrict__ out0) {
  const int b  = blockIdx.z;
  const int c0 = blockIdx.y * 64;
  const int l0 = blockIdx.x * 64;
  const int tid = threadIdx.x;
  const int tx = tid & 15;   // -> l group
  const int ty = tid >> 4;   // -> c group

  __shared__ float cs[16][68];
  __shared__ float fw[16][68];

  float acc[4][4];
#pragma unroll
  for (int i = 0; i < 4; ++i)
#pragma unroll
    for (int j = 0; j < 4; ++j) acc[i][j] = 0.f;

  for (int a0 = 0; a0 < NDW; a0 += 16) {
    __syncthreads();
    for (int idx = tid; idx < 1024; idx += 256) {
      int l = idx >> 4, i = idx & 15;
      cs[i][l] = ctx[((size_t)b * NL + l0 + l) * NDW + a0 + i];
    }
    for (int idx = tid; idx < 1024; idx += 256) {
      int c = idx >> 4, i = idx & 15;
      fw[i][c] = fw2g[(size_t)(c0 + c) * NDW + a0 + i];
    }
    __syncthreads();
#pragma unroll
    for (int i = 0; i < 16; ++i) {
      float4 lv = *(const float4*)&cs[i][tx * 4];
      float4 cv = *(const float4*)&fw[i][ty * 4];
      float lr[4] = {lv.x, lv.y, lv.z, lv.w};
      float cr[4] = {cv.x, cv.y, cv.z, cv.w};
#pragma unroll
      for (int cc = 0; cc < 4; ++cc)
#pragma unroll
        for (int r = 0; r < 4; ++r) acc[cc][r] += cr[cc] * lr[r];
    }
  }

#pragma unroll
  for (int cc = 0; cc < 4; ++cc) {
    int c = c0 + ty * 4 + cc;
    size_t base = ((size_t)b * NDW + c) * NL + l0 + tx * 4;
    float4 hv = *(const float4*)&h[base];
    float4 xv = *(const float4*)&x[base];
    float bias = fb2[c];
    float4 o4;
    o4.x = acc[cc][0] + bias + hv.x + xv.x;
    o4.y = acc[cc][1] + bias + hv.y + xv.y;
    o4.z = acc[cc][2] + bias + hv.z + xv.z;
    o4.w = acc[cc][3] + bias + hv.w + xv.w;
    *(float4*)&out0[base] = o4;
  }
}

// ---------------------------------------------------------------------------
extern "C" void kernel_launch(void* const* d_in, const int* in_sizes, int n_in,
                              void* d_out, int out_size, void* d_ws, size_t ws_size,
                              hipStream_t stream) {
  const float* x      = (const float*)d_in[0];
  const float* we     = (const float*)d_in[1];
  const float* img    = (const float*)d_in[2];
  const float* conv_v = (const float*)d_in[4];
  const float* conv_g = (const float*)d_in[5];
  const float* conv_b = (const float*)d_in[6];
  const float* fc1_w  = (const float*)d_in[7];
  const float* fc1_b  = (const float*)d_in[8];
  const float* fc2_w  = (const float*)d_in[9];
  const float* fc2_b  = (const float*)d_in[10];

  float* out0     = (float*)d_out;          // (16,512,1024)
  float* out_we   = out0 + 8388608;         // (16,1024,512)
  float* out_img  = out_we + 8388608;       // (16,512,14,14)
  float* out_attn = out_img + 1605632;      // (16,1024,196)

  float* ws = (float*)d_ws;
  ushort_t* wperm = (ushort_t*)ws;          // 5*1024*512 ushort (5.2MB) in 10.5MB region
  float* h  = ws + 2621440;                 // 16*512*1024 fp32
  float* q  = h + 8388608;                  // 16*1024*512 fp32
  ushort_t* xT = (ushort_t*)q;              // bf16 xT overlays q (dead before fc1 writes q)
  float* ctx = q;                           // aliases q (per-block q rows staged to LDS first)

  wnorm_kernel<<<dim3(NCOUT), 256, 0, stream>>>(conv_v, conv_g, wperm);
  xpose_kernel<<<dim3(16, 8, NB), 256, 0, stream>>>(x, xT);
  conv_glu_mfma<<<dim3(8, 4, NB), 256, 0, stream>>>(xT, wperm, conv_b, h);
  fc1_kernel<<<dim3(16, 8, NB), 256, 0, stream>>>(h, fc1_w, fc1_b, we, q);
  attn_kernel<<<dim3(64, NB), 256, 0, stream>>>(q, img, ctx, out_attn);
  fc2_kernel<<<dim3(16, 8, NB), 256, 0, stream>>>(ctx, fc2_w, fc2_b, h, x, out0);

  hipMemcpyAsync(out_we, we, (size_t)8388608 * sizeof(float),
                 hipMemcpyDeviceToDevice, stream);
  hipMemcpyAsync(out_img, img, (size_t)1605632 * sizeof(float),
                 hipMemcpyDeviceToDevice, stream);
}

// Round 3
// 430.003 us; speedup vs baseline: 5.6411x; 2.8629x over previous
//
#include <hip/hip_runtime.h>
#include <math.h>

// Sizes (fixed for this problem)
#define NB   16
#define NCIN 512
#define NL   1024
#define NCOUT 1024
#define NK   5
#define NDW  512
#define NHW  196
#define NP   208   // HW padded to 13 n-tiles of 16
#define NPK  224   // HW padded to 7 k-chunks of 32

typedef unsigned short ushort_t;
typedef unsigned int uint_t;
typedef __attribute__((ext_vector_type(8))) short bf16x8;
typedef __attribute__((ext_vector_type(4))) float f32x4;

static __device__ __forceinline__ ushort_t f2bf(float f) {
  uint_t u = __builtin_bit_cast(uint_t, f);
  u += 0x7fff + ((u >> 16) & 1);  // round-to-nearest-even
  return (ushort_t)(u >> 16);
}
static __device__ __forceinline__ float bf2f(ushort_t u) {
  uint_t v = ((uint_t)u) << 16;
  return __builtin_bit_cast(float, v);
}

// ---------------------------------------------------------------------------
// K1: weight norm -> permuted bf16 weights.
// wperm[dk][co][ci] = bf16( g[co]/||v[co]|| * v[co][ci][dk] )
// ---------------------------------------------------------------------------
__global__ __launch_bounds__(256) void wnorm_kernel(
    const float* __restrict__ v, const float* __restrict__ g,
    ushort_t* __restrict__ wperm) {
  const int o = blockIdx.x;
  const float* vr = v + (size_t)o * (NCIN * NK);
  float s = 0.f;
  for (int j = threadIdx.x; j < NCIN * NK; j += 256) {
    float t = vr[j];
    s += t * t;
  }
  for (int off = 32; off; off >>= 1) s += __shfl_down(s, off, 64);
  __shared__ float red[4];
  __shared__ float scale_s;
  const int wid = threadIdx.x >> 6;
  if ((threadIdx.x & 63) == 0) red[wid] = s;
  __syncthreads();
  if (threadIdx.x == 0) {
    float tot = red[0] + red[1] + red[2] + red[3];
    scale_s = g[o] / sqrtf(tot);
  }
  __syncthreads();
  const float scale = scale_s;
#pragma unroll
  for (int dk = 0; dk < NK; ++dk) {
    for (int ci = threadIdx.x; ci < NCIN; ci += 256) {
      wperm[((size_t)dk * NCOUT + o) * NCIN + ci] = f2bf(vr[ci * NK + dk] * scale);
    }
  }
}

// ---------------------------------------------------------------------------
// K2a: transpose + bf16 convert:  xT[b][l][ci] = bf16(x[b][ci][l])
// ---------------------------------------------------------------------------
__global__ __launch_bounds__(256) void xpose_kernel(
    const float* __restrict__ x, ushort_t* __restrict__ xT) {
  const int b = blockIdx.z;
  const int ci0 = blockIdx.y * 64;
  const int l0 = blockIdx.x * 64;
  const int tid = threadIdx.x;
  __shared__ float t[64][65];
  const float* xb = x + ((size_t)b * NCIN + ci0) * NL + l0;
#pragma unroll
  for (int r = 0; r < 4; ++r) {
    int row = r * 16 + (tid >> 4);
    int col = (tid & 15) * 4;
    float4 v = *(const float4*)&xb[(size_t)row * NL + col];
    t[row][col + 0] = v.x; t[row][col + 1] = v.y;
    t[row][col + 2] = v.z; t[row][col + 3] = v.w;
  }
  __syncthreads();
  ushort_t* xo = xT + ((size_t)b * NL + l0) * NCIN + ci0;
#pragma unroll
  for (int r = 0; r < 4; ++r) {
    int lrow = r * 16 + (tid >> 4);
    int cic = (tid & 15) * 4;
    ushort4 o4;
    o4.x = f2bf(t[cic + 0][lrow]);
    o4.y = f2bf(t[cic + 1][lrow]);
    o4.z = f2bf(t[cic + 2][lrow]);
    o4.w = f2bf(t[cic + 3][lrow]);
    *(ushort4*)&xo[(size_t)lrow * NCIN + cic] = o4;
  }
}

// ---------------------------------------------------------------------------
// K-prep: fc1_w / fc2_w -> bf16 (both [512][512], row-major, k=last dim)
// ---------------------------------------------------------------------------
__global__ __launch_bounds__(256) void wcvt_kernel(
    const float* __restrict__ w1, const float* __restrict__ w2,
    ushort_t* __restrict__ w1bf, ushort_t* __restrict__ w2bf) {
  const int i = (blockIdx.x * 256 + threadIdx.x) * 4;  // grid 256 -> covers 262144
  {
    float4 v = *(const float4*)&w1[i];
    ushort4 o; o.x = f2bf(v.x); o.y = f2bf(v.y); o.z = f2bf(v.z); o.w = f2bf(v.w);
    *(ushort4*)&w1bf[i] = o;
  }
  {
    float4 v = *(const float4*)&w2[i];
    ushort4 o; o.x = f2bf(v.x); o.y = f2bf(v.y); o.z = f2bf(v.z); o.w = f2bf(v.w);
    *(ushort4*)&w2bf[i] = o;
  }
}

// ---------------------------------------------------------------------------
// K-prep: feat transforms.
//  fThi/fTlo[b][p][a] : split-bf16 transpose of feat (rows p>=196 zeroed)
//  fbf[b][a][p']      : bf16 feat, p' padded to 224 with zeros
// grid (8 a-tiles, 16 b)
// ---------------------------------------------------------------------------
__global__ __launch_bounds__(256) void ftrans_kernel(
    const float* __restrict__ feat, ushort_t* __restrict__ fThi,
    ushort_t* __restrict__ fTlo, ushort_t* __restrict__ fbf) {
  const int b = blockIdx.y;
  const int a0 = blockIdx.x * 64;
  const int tid = threadIdx.x;
  __shared__ float t[64][200];

  const float* fb_ = feat + ((size_t)b * NDW + a0) * NHW;
#pragma unroll
  for (int pp = 0; pp < 16; ++pp) {
    int row = pp * 4 + (tid >> 6);
#pragma unroll
    for (int cc = 0; cc < 4; ++cc) {
      int col = cc * 64 + (tid & 63);
      if (col < NHW) t[row][col] = fb_[(size_t)row * NHW + col];
    }
  }
  __syncthreads();

  // fT writes: 208 p-rows x 64 a
  for (int pp = 0; pp < 13; ++pp) {
    int p = pp * 16 + (tid >> 4);
    int j = (tid & 15) * 4;
    ushort4 hi4, lo4;
#pragma unroll
    for (int k = 0; k < 4; ++k) {
      float v = (p < NHW) ? t[j + k][p] : 0.f;
      ushort_t h = f2bf(v);
      float lof = v - bf2f(h);
      ushort_t l = f2bf(lof);
      ((ushort_t*)&hi4)[k] = h;
      ((ushort_t*)&lo4)[k] = l;
    }
    size_t base = ((size_t)b * NP + p) * NDW + a0 + j;
    *(ushort4*)&fThi[base] = hi4;
    *(ushort4*)&fTlo[base] = lo4;
  }

  // fbf writes: 64 a-rows x 224 p
#pragma unroll
  for (int cc = 0; cc < 4; ++cc) {
    int col = cc * 64 + (tid & 63);
    if (col < NPK) {
#pragma unroll
      for (int rr = 0; rr < 16; ++rr) {
        int al = rr * 4 + (tid >> 6);
        float v = (col < NHW) ? t[al][col] : 0.f;
        fbf[((size_t)b * NDW + a0 + al) * NPK + col] = f2bf(v);
      }
    }
  }
}

// ---------------------------------------------------------------------------
// K2b: conv1d + bias + GLU via bf16 MFMA implicit GEMM.
// Writes hbfT[b][l][c] = bf16(h) (transposed layout for fc1 A-operand & fc2 residual)
// ---------------------------------------------------------------------------
__global__ __launch_bounds__(256, 2) void conv_glu_mfma(
    const ushort_t* __restrict__ xT, const ushort_t* __restrict__ wperm,
    const float* __restrict__ conv_b, ushort_t* __restrict__ hbfT) {
  const int b  = blockIdx.z;
  const int c0 = blockIdx.y * 128;
  const int l0 = blockIdx.x * 128;
  const int tid = threadIdx.x;
  const int wid = tid >> 6;
  const int lane = tid & 63;
  const int wl = wid & 1;
  const int wc = wid >> 1;
  const int quad = lane >> 4;
  const int l16 = lane & 15;

  __shared__ ushort_t lx[128][72];
  __shared__ ushort_t lw[256][72];

  f32x4 accA[4][4], accB[4][4];
#pragma unroll
  for (int mt = 0; mt < 4; ++mt)
#pragma unroll
    for (int nt = 0; nt < 4; ++nt) {
      accA[mt][nt] = (f32x4){0.f, 0.f, 0.f, 0.f};
      accB[mt][nt] = (f32x4){0.f, 0.f, 0.f, 0.f};
    }

  const ushort_t* xTb = xT + (size_t)b * NL * NCIN;

  for (int dk = 0; dk < NK; ++dk) {
    const int lbase = l0 + dk - 4;
    const ushort_t* wpb = wperm + (size_t)dk * NCOUT * NCIN;
    for (int ci0 = 0; ci0 < NCIN; ci0 += 64) {
      __syncthreads();
#pragma unroll
      for (int it = 0; it < 4; ++it) {
        int t = tid + it * 256;
        int r = t >> 3, seg = t & 7;
        int gl = lbase + r;
        uint4 v = make_uint4(0u, 0u, 0u, 0u);
        if (gl >= 0)
          v = *(const uint4*)(xTb + (size_t)gl * NCIN + ci0 + seg * 8);
        *(uint4*)&lx[r][seg * 8] = v;
      }
#pragma unroll
      for (int it = 0; it < 8; ++it) {
        int t = tid + it * 256;
        int r = t >> 3, seg = t & 7;
        int co = (it < 4) ? (c0 + r) : (384 + c0 + r);
        uint4 v = *(const uint4*)(wpb + (size_t)co * NCIN + ci0 + seg * 8);
        *(uint4*)&lw[r][seg * 8] = v;
      }
      __syncthreads();
#pragma unroll
      for (int ks = 0; ks < 2; ++ks) {
        bf16x8 af[4];
#pragma unroll
        for (int mt = 0; mt < 4; ++mt)
          af[mt] = *(const bf16x8*)&lx[wl * 64 + mt * 16 + l16][ks * 32 + quad * 8];
#pragma unroll
        for (int nt = 0; nt < 4; ++nt) {
          bf16x8 bfa = *(const bf16x8*)&lw[wc * 64 + nt * 16 + l16][ks * 32 + quad * 8];
          bf16x8 bfb = *(const bf16x8*)&lw[128 + wc * 64 + nt * 16 + l16][ks * 32 + quad * 8];
#pragma unroll
          for (int mt = 0; mt < 4; ++mt) {
            accA[mt][nt] = __builtin_amdgcn_mfma_f32_16x16x32_bf16(af[mt], bfa, accA[mt][nt], 0, 0, 0);
            accB[mt][nt] = __builtin_amdgcn_mfma_f32_16x16x32_bf16(af[mt], bfb, accB[mt][nt], 0, 0, 0);
          }
        }
      }
    }
  }

  // epilogue: GLU, write hbfT[b][l][co] (co < 512)
#pragma unroll
  for (int nt = 0; nt < 4; ++nt) {
    const int co = c0 + wc * 64 + nt * 16 + l16;
    const float ba = conv_b[co];
    const float bb = conv_b[co + 512];
#pragma unroll
    for (int mt = 0; mt < 4; ++mt) {
      const int l = l0 + wl * 64 + mt * 16 + quad * 4;
      f32x4 a4 = accA[mt][nt];
      f32x4 b4 = accB[mt][nt];
#pragma unroll
      for (int r = 0; r < 4; ++r) {
        float aa = a4[r] + ba, bg = b4[r] + bb;
        float hv = aa * (1.f / (1.f + __expf(-bg)));
        hbfT[((size_t)b * NL + l + r) * NDW + co] = f2bf(hv);
      }
    }
  }
}

// ---------------------------------------------------------------------------
// K3: fc1 MFMA.  q[l][a] = sum_c hbfT[l][c]*w1bf[a][c] + b[a] + we[l][a]
// Writes split q: qhi/qlo bf16 [b][l][a].
// ---------------------------------------------------------------------------
__global__ __launch_bounds__(256, 2) void fc1_mfma(
    const ushort_t* __restrict__ hbfT, const ushort_t* __restrict__ w1bf,
    const float* __restrict__ fb, const float* __restrict__ we,
    ushort_t* __restrict__ qhi, ushort_t* __restrict__ qlo) {
  const int b  = blockIdx.z;
  const int a0 = blockIdx.y * 128;
  const int l0 = blockIdx.x * 128;
  const int tid = threadIdx.x;
  const int wid = tid >> 6;
  const int lane = tid & 63;
  const int wl = wid & 1;
  const int wc = wid >> 1;
  const int quad = lane >> 4;
  const int l16 = lane & 15;

  __shared__ ushort_t la[128][72];
  __shared__ ushort_t lb[128][72];

  f32x4 acc[4][4];
#pragma unroll
  for (int mt = 0; mt < 4; ++mt)
#pragma unroll
    for (int nt = 0; nt < 4; ++nt) acc[mt][nt] = (f32x4){0.f, 0.f, 0.f, 0.f};

  const ushort_t* hb = hbfT + (size_t)b * NL * NDW;

  for (int c0 = 0; c0 < NDW; c0 += 64) {
    __syncthreads();
#pragma unroll
    for (int it = 0; it < 4; ++it) {
      int t = tid + it * 256;
      int r = t >> 3, seg = t & 7;
      *(uint4*)&la[r][seg * 8] = *(const uint4*)(hb + (size_t)(l0 + r) * NDW + c0 + seg * 8);
    }
#pragma unroll
    for (int it = 0; it < 4; ++it) {
      int t = tid + it * 256;
      int r = t >> 3, seg = t & 7;
      *(uint4*)&lb[r][seg * 8] = *(const uint4*)(w1bf + (size_t)(a0 + r) * NDW + c0 + seg * 8);
    }
    __syncthreads();
#pragma unroll
    for (int ks = 0; ks < 2; ++ks) {
      bf16x8 af[4];
#pragma unroll
      for (int mt = 0; mt < 4; ++mt)
        af[mt] = *(const bf16x8*)&la[wl * 64 + mt * 16 + l16][ks * 32 + quad * 8];
#pragma unroll
      for (int nt = 0; nt < 4; ++nt) {
        bf16x8 bf = *(const bf16x8*)&lb[wc * 64 + nt * 16 + l16][ks * 32 + quad * 8];
#pragma unroll
        for (int mt = 0; mt < 4; ++mt)
          acc[mt][nt] = __builtin_amdgcn_mfma_f32_16x16x32_bf16(af[mt], bf, acc[mt][nt], 0, 0, 0);
      }
    }
  }

#pragma unroll
  for (int nt = 0; nt < 4; ++nt) {
    const int a = a0 + wc * 64 + nt * 16 + l16;
    const float bias = fb[a];
#pragma unroll
    for (int mt = 0; mt < 4; ++mt) {
      const int l = l0 + wl * 64 + mt * 16 + quad * 4;
#pragma unroll
      for (int r = 0; r < 4; ++r) {
        size_t idx = ((size_t)b * NL + l + r) * NDW + a;
        float qv = acc[mt][nt][r] + bias + we[idx];
        ushort_t h = f2bf(qv);
        float lof = qv - bf2f(h);
        qhi[idx] = h;
        qlo[idx] = f2bf(lof);
      }
    }
  }
}

// ---------------------------------------------------------------------------
// K4a: scores + softmax, 3-pass split-bf16 MFMA.
//   S[l][p] = qh·fh + ql·fh + qh·fl  (fp32 acc), softmax over p -> out_attn fp32
// Block: 64 l x 208 p; 4 waves, wave = 16 l (1 m-tile) x 13 n-tiles.
// grid (16 l-tiles, 16 b)
// ---------------------------------------------------------------------------
__global__ __launch_bounds__(256) void score_softmax(
    const ushort_t* __restrict__ qhi, const ushort_t* __restrict__ qlo,
    const ushort_t* __restrict__ fThi, const ushort_t* __restrict__ fTlo,
    float* __restrict__ out_attn) {
  const int b  = blockIdx.y;
  const int l0 = blockIdx.x * 64;
  const int tid = threadIdx.x;
  const int wid = tid >> 6;
  const int lane = tid & 63;
  const int quad = lane >> 4;
  const int l16 = lane & 15;

  __shared__ ushort_t qh[64][36], ql[64][36];
  __shared__ ushort_t fh[208][36], fl[208][36];

  f32x4 acc[13];
#pragma unroll
  for (int nt = 0; nt < 13; ++nt) acc[nt] = (f32x4){0.f, 0.f, 0.f, 0.f};

  for (int kc = 0; kc < 16; ++kc) {
    const int a0 = kc * 32;
    __syncthreads();
    {
      int r = tid >> 2, seg = tid & 3;
      size_t src = ((size_t)b * NL + l0 + r) * NDW + a0 + seg * 8;
      *(uint4*)&qh[r][seg * 8] = *(const uint4*)(qhi + src);
      *(uint4*)&ql[r][seg * 8] = *(const uint4*)(qlo + src);
#pragma unroll
      for (int it = 0; it < 4; ++it) {
        int row = it * 64 + (tid >> 2);
        if (row < NP) {
          size_t fsrc = ((size_t)b * NP + row) * NDW + a0 + seg * 8;
          *(uint4*)&fh[row][seg * 8] = *(const uint4*)(fThi + fsrc);
          *(uint4*)&fl[row][seg * 8] = *(const uint4*)(fTlo + fsrc);
        }
      }
    }
    __syncthreads();
    bf16x8 ah = *(const bf16x8*)&qh[wid * 16 + l16][quad * 8];
    bf16x8 al = *(const bf16x8*)&ql[wid * 16 + l16][quad * 8];
#pragma unroll
    for (int nt = 0; nt < 13; ++nt) {
      bf16x8 bh = *(const bf16x8*)&fh[nt * 16 + l16][quad * 8];
      bf16x8 bl = *(const bf16x8*)&fl[nt * 16 + l16][quad * 8];
      acc[nt] = __builtin_amdgcn_mfma_f32_16x16x32_bf16(ah, bh, acc[nt], 0, 0, 0);
      acc[nt] = __builtin_amdgcn_mfma_f32_16x16x32_bf16(al, bh, acc[nt], 0, 0, 0);
      acc[nt] = __builtin_amdgcn_mfma_f32_16x16x32_bf16(ah, bl, acc[nt], 0, 0, 0);
    }
  }

  // softmax per row; D layout: row = quad*4 + r, col p = nt*16 + l16
  const bool v12 = (l16 < 4);  // nt=12 valid only for p=192+l16 < 196
#pragma unroll
  for (int r = 0; r < 4; ++r) {
    float mx = -1e30f;
#pragma unroll
    for (int nt = 0; nt < 12; ++nt) mx = fmaxf(mx, acc[nt][r]);
    if (v12) mx = fmaxf(mx, acc[12][r]);
#pragma unroll
    for (int off = 1; off < 16; off <<= 1) mx = fmaxf(mx, __shfl_xor(mx, off, 16));
    float ex[13];
    float sum = 0.f;
#pragma unroll
    for (int nt = 0; nt < 12; ++nt) { ex[nt] = __expf(acc[nt][r] - mx); sum += ex[nt]; }
    ex[12] = v12 ? __expf(acc[12][r] - mx) : 0.f;
    sum += ex[12];
#pragma unroll
    for (int off = 1; off < 16; off <<= 1) sum += __shfl_xor(sum, off, 16);
    const float inv = 1.f / sum;
    const int l = l0 + wid * 16 + quad * 4 + r;
    float* ao = out_attn + ((size_t)b * NL + l) * NHW;
#pragma unroll
    for (int nt = 0; nt < 13; ++nt) {
      int p = nt * 16 + l16;
      if (p < NHW) ao[p] = ex[nt] * inv;
    }
  }
}

// ---------------------------------------------------------------------------
// K4b: ctx MFMA.  ctx[l][a] = sum_p attn[l][p] * fbf[a][p]   (K padded to 224)
// A staged from out_attn fp32 (cvt to bf16), B from fbf.  Writes ctx_bf[b][l][a].
// ---------------------------------------------------------------------------
__global__ __launch_bounds__(256, 2) void ctx_mfma(
    const float* __restrict__ attn, const ushort_t* __restrict__ fbf,
    ushort_t* __restrict__ ctx_bf) {
  const int b  = blockIdx.z;
  const int a0 = blockIdx.y * 128;
  const int l0 = blockIdx.x * 128;
  const int tid = threadIdx.x;
  const int wid = tid >> 6;
  const int lane = tid & 63;
  const int wl = wid & 1;
  const int wc = wid >> 1;
  const int quad = lane >> 4;
  const int l16 = lane & 15;

  __shared__ ushort_t la[128][36];
  __shared__ ushort_t lb[128][36];

  f32x4 acc[4][4];
#pragma unroll
  for (int mt = 0; mt < 4; ++mt)
#pragma unroll
    for (int nt = 0; nt < 4; ++nt) acc[mt][nt] = (f32x4){0.f, 0.f, 0.f, 0.f};

  for (int kc = 0; kc < 7; ++kc) {
    const int p0 = kc * 32;
    __syncthreads();
#pragma unroll
    for (int it = 0; it < 2; ++it) {
      int r = it * 64 + (tid >> 2), seg = tid & 3;
      int pb = p0 + seg * 8;
      const float* src = attn + ((size_t)b * NL + l0 + r) * NHW + pb;
      ushort4 o[2];
      if (pb + 7 < NHW) {
        float4 v0 = *(const float4*)src;
        float4 v1 = *(const float4*)(src + 4);
        o[0].x = f2bf(v0.x); o[0].y = f2bf(v0.y); o[0].z = f2bf(v0.z); o[0].w = f2bf(v0.w);
        o[1].x = f2bf(v1.x); o[1].y = f2bf(v1.y); o[1].z = f2bf(v1.z); o[1].w = f2bf(v1.w);
      } else {
#pragma unroll
        for (int k = 0; k < 8; ++k) {
          float v = (pb + k < NHW) ? src[k] : 0.f;
          ((ushort_t*)o)[k] = f2bf(v);
        }
      }
      *(uint4*)&la[r][seg * 8] = *(uint4*)o;
      // B tile: fbf rows a
      const ushort_t* fsrc = fbf + ((size_t)b * NDW + a0 + r) * NPK + pb;
      *(uint4*)&lb[r][seg * 8] = *(const uint4*)fsrc;
    }
    __syncthreads();
    bf16x8 af[4];
#pragma unroll
    for (int mt = 0; mt < 4; ++mt)
      af[mt] = *(const bf16x8*)&la[wl * 64 + mt * 16 + l16][quad * 8];
#pragma unroll
    for (int nt = 0; nt < 4; ++nt) {
      bf16x8 bf = *(const bf16x8*)&lb[wc * 64 + nt * 16 + l16][quad * 8];
#pragma unroll
      for (int mt = 0; mt < 4; ++mt)
        acc[mt][nt] = __builtin_amdgcn_mfma_f32_16x16x32_bf16(af[mt], bf, acc[mt][nt], 0, 0, 0);
    }
  }

#pragma unroll
  for (int nt = 0; nt < 4; ++nt) {
    const int a = a0 + wc * 64 + nt * 16 + l16;
#pragma unroll
    for (int mt = 0; mt < 4; ++mt) {
      const int l = l0 + wl * 64 + mt * 16 + quad * 4;
#pragma unroll
      for (int r = 0; r < 4; ++r)
        ctx_bf[((size_t)b * NL + l + r) * NDW + a] = f2bf(acc[mt][nt][r]);
    }
  }
}

// ---------------------------------------------------------------------------
// K5: fc2 MFMA.  out[c][l] = sum_a w2bf[c][a]*ctx_bf[l][a] + fb2[c] + h + x
// M = c (A side), N = l (B side).
// ---------------------------------------------------------------------------
__global__ __launch_bounds__(256, 2) void fc2_mfma(
    const ushort_t* __restrict__ w2bf, const ushort_t* __restrict__ ctx_bf,
    const float* __restrict__ fb2, const ushort_t* __restrict__ hbfT,
    const float* __restrict__ x, float* __restrict__ out0) {
  const int b  = blockIdx.z;
  const int c0 = blockIdx.y * 128;
  const int l0 = blockIdx.x * 128;
  const int tid = threadIdx.x;
  const int wid = tid >> 6;
  const int lane = tid & 63;
  const int wl = wid & 1;   // c sub-tile
  const int wc = wid >> 1;  // l sub-tile
  const int quad = lane >> 4;
  const int l16 = lane & 15;

  __shared__ ushort_t la[128][72];
  __shared__ ushort_t lb[128][72];

  f32x4 acc[4][4];
#pragma unroll
  for (int mt = 0; mt < 4; ++mt)
#pragma unroll
    for (int nt = 0; nt < 4; ++nt) acc[mt][nt] = (f32x4){0.f, 0.f, 0.f, 0.f};

  for (int a0 = 0; a0 < NDW; a0 += 64) {
    __syncthreads();
#pragma unroll
    for (int it = 0; it < 4; ++it) {
      int t = tid + it * 256;
      int r = t >> 3, seg = t & 7;
      *(uint4*)&la[r][seg * 8] = *(const uint4*)(w2bf + (size_t)(c0 + r) * NDW + a0 + seg * 8);
    }
#pragma unroll
    for (int it = 0; it < 4; ++it) {
      int t = tid + it * 256;
      int r = t >> 3, seg = t & 7;
      *(uint4*)&lb[r][seg * 8] =
          *(const uint4*)(ctx_bf + ((size_t)b * NL + l0 + r) * NDW + a0 + seg * 8);
    }
    __syncthreads();
#pragma unroll
    for (int ks = 0; ks < 2; ++ks) {
      bf16x8 af[4];
#pragma unroll
      for (int mt = 0; mt < 4; ++mt)
        af[mt] = *(const bf16x8*)&la[wl * 64 + mt * 16 + l16][ks * 32 + quad * 8];
#pragma unroll
      for (int nt = 0; nt < 4; ++nt) {
        bf16x8 bf = *(const bf16x8*)&lb[wc * 64 + nt * 16 + l16][ks * 32 + quad * 8];
#pragma unroll
        for (int mt = 0; mt < 4; ++mt)
          acc[mt][nt] = __builtin_amdgcn_mfma_f32_16x16x32_bf16(af[mt], bf, acc[mt][nt], 0, 0, 0);
      }
    }
  }

  // epilogue: row = c, col = l
#pragma unroll
  for (int mt = 0; mt < 4; ++mt) {
    const int cb = c0 + wl * 64 + mt * 16 + quad * 4;
    float4 bias4 = *(const float4*)&fb2[cb];
#pragma unroll
    for (int nt = 0; nt < 4; ++nt) {
      const int l = l0 + wc * 64 + nt * 16 + l16;
      ushort4 h4 = *(const ushort4*)&hbfT[((size_t)b * NL + l) * NDW + cb];
      const float bias[4] = {bias4.x, bias4.y, bias4.z, bias4.w};
      const ushort_t hs[4] = {h4.x, h4.y, h4.z, h4.w};
#pragma unroll
      for (int r = 0; r < 4; ++r) {
        size_t idx = ((size_t)b * NDW + cb + r) * NL + l;
        out0[idx] = acc[mt][nt][r] + bias[r] + bf2f(hs[r]) + x[idx];
      }
    }
  }
}

// ---------------------------------------------------------------------------
extern "C" void kernel_launch(void* const* d_in, const int* in_sizes, int n_in,
                              void* d_out, int out_size, void* d_ws, size_t ws_size,
                              hipStream_t stream) {
  const float* x      = (const float*)d_in[0];
  const float* we     = (const float*)d_in[1];
  const float* img    = (const float*)d_in[2];
  const float* conv_v = (const float*)d_in[4];
  const float* conv_g = (const float*)d_in[5];
  const float* conv_b = (const float*)d_in[6];
  const float* fc1_w  = (const float*)d_in[7];
  const float* fc1_b  = (const float*)d_in[8];
  const float* fc2_w  = (const float*)d_in[9];
  const float* fc2_b  = (const float*)d_in[10];

  float* out0     = (float*)d_out;          // (16,512,1024)
  float* out_we   = out0 + 8388608;         // (16,1024,512)
  float* out_img  = out_we + 8388608;       // (16,512,14,14)
  float* out_attn = out_img + 1605632;      // (16,1024,196)

  // Workspace layout (ushort units). Total 61.9 MB < 77.6 MB proven available.
  ushort_t* wsu = (ushort_t*)d_ws;
  ushort_t* qhi   = wsu;                    // 8,388,608   [fc1 -> score]
  ushort_t* qlo   = wsu + 8388608;          // 8,388,608   [fc1 -> score]
  ushort_t* wperm = wsu;                    // 2,621,440   [phase A alias of qhi]
  ushort_t* xT    = wsu + 2621440;          // 8,388,608   [phase A alias]
  ushort_t* ctx_b = wsu;                    // 8,388,608   [ctx -> fc2; qhi dead]
  ushort_t* hbfT  = wsu + 16777216;         // 8,388,608   [conv -> fc2]
  ushort_t* w1bf  = wsu + 25165824;         // 262,144
  ushort_t* w2bf  = wsu + 25428968 - 263144 + 262144 + 144;  // placeholder fixed below
  w2bf = wsu + 25165824 + 262144;           // 262,144
  ushort_t* fThi  = wsu + 25690112;         // 1,703,936
  ushort_t* fTlo  = wsu + 27394048;         // 1,703,936
  ushort_t* fbf   = wsu + 29097984;         // 1,835,008  -> ends 30,932,992

  wnorm_kernel<<<dim3(NCOUT), 256, 0, stream>>>(conv_v, conv_g, wperm);
  xpose_kernel<<<dim3(16, 8, NB), 256, 0, stream>>>(x, xT);
  wcvt_kernel<<<dim3(256), 256, 0, stream>>>(fc1_w, fc2_w, w1bf, w2bf);
  ftrans_kernel<<<dim3(8, NB), 256, 0, stream>>>(img, fThi, fTlo, fbf);

  conv_glu_mfma<<<dim3(8, 4, NB), 256, 0, stream>>>(xT, wperm, conv_b, hbfT);
  fc1_mfma<<<dim3(8, 4, NB), 256, 0, stream>>>(hbfT, w1bf, fc1_b, we, qhi, qlo);
  score_softmax<<<dim3(16, NB), 256, 0, stream>>>(qhi, qlo, fThi, fTlo, out_attn);
  ctx_mfma<<<dim3(8, 4, NB), 256, 0, stream>>>(out_attn, fbf, ctx_b);
  fc2_mfma<<<dim3(8, 4, NB), 256, 0, stream>>>(w2bf, ctx_b, fc2_b, hbfT, x, out0);

  hipMemcpyAsync(out_we, we, (size_t)8388608 * sizeof(float),
                 hipMemcpyDeviceToDevice, stream);
  hipMemcpyAsync(out_img, img, (size_t)1605632 * sizeof(float),
                 hipMemcpyDeviceToDevice, stream);
}